// Round 7
// baseline (39.438 us; speedup 1.0000x reference)
//
#include <hip/hip_runtime.h>

#define LENGTH   256
#define VOLUME   (LENGTH * LENGTH)
#define N_STATES 256
#define ACTION_SHIFT_F 131072.0f   // 2 * BETA * VOLUME, BETA = 1
#define BPS      8                 // blocks per state (32 rows each)
#define THREADS  256
#define RPW      8                 // rows per wave: 4 waves * 8 = 32 rows/block

// R6 structure (2048x256 grid, register row-carry, scalar-load left neighbor,
// two-kernel fold) with ONE change: __launch_bounds__(256, 8) caps VGPR at 64
// -> 8 waves/SIMD (vs ~4), doubling latency tolerance. Row loop at unroll 2
// so the compiler fits the cap without scratch spills; TLP replaces ILP.
__global__ __launch_bounds__(THREADS, 8)
void action_partial(const float* __restrict__ state, float* __restrict__ ws)
{
    const int blk = blockIdx.x;
    const int n   = blk >> 3;      // state index
    const int b   = blk & 7;       // 32-row band within state
    const float* __restrict__ theta = state + (size_t)n * (2 * VOLUME);
    const float* __restrict__ phi   = theta + VOLUME;

    const int wave = threadIdx.x >> 6;
    const int lane = threadIdx.x & 63;
    const int r0   = b * 32 + wave * RPW;
    const int c    = lane * 4;
    const int lc   = (c == 0) ? (LENGTH - 1) : (c - 1);  // left col of element 0

    // ---- prime: row r0-1 (wraps at lattice edge) becomes "up" for row r0
    float sU[4], cU[4], pU[4];
    {
        const int rp = (r0 + LENGTH - 1) & (LENGTH - 1);
        const float4 tp = *reinterpret_cast<const float4*>(theta + rp * LENGTH + c);
        const float4 pp = *reinterpret_cast<const float4*>(phi   + rp * LENGTH + c);
        const float tv[4] = {tp.x, tp.y, tp.z, tp.w};
        #pragma unroll
        for (int j = 0; j < 4; ++j) __sincosf(tv[j], &sU[j], &cU[j]);
        pU[0] = pp.x; pU[1] = pp.y; pU[2] = pp.z; pU[3] = pp.w;
    }

    // ---- 2-deep pipelined row march
    float4 tc = *reinterpret_cast<const float4*>(theta + r0 * LENGTH + c);
    float4 pc = *reinterpret_cast<const float4*>(phi   + r0 * LENGTH + c);
    float  tl = theta[r0 * LENGTH + lc];
    float  pl = phi  [r0 * LENGTH + lc];

    float acc0 = 0.0f, acc1 = 0.0f;
    #pragma unroll 2
    for (int k = 0; k < RPW; ++k) {
        const float4 TC = tc, PC = pc;
        const float  TL = tl, PL = pl;
        if (k < RPW - 1) {  // issue next row's loads before current compute
            const int r = r0 + k + 1;
            tc = *reinterpret_cast<const float4*>(theta + r * LENGTH + c);
            pc = *reinterpret_cast<const float4*>(phi   + r * LENGTH + c);
            tl = theta[r * LENGTH + lc];
            pl = phi  [r * LENGTH + lc];
        }

        const float tv[4] = {TC.x, TC.y, TC.z, TC.w};
        const float pv[4] = {PC.x, PC.y, PC.z, PC.w};

        float s[4], cc[4];
        #pragma unroll
        for (int j = 0; j < 4; ++j) __sincosf(tv[j], &s[j], &cc[j]);
        float sl, cl;
        __sincosf(TL, &sl, &cl);

        // vertical (up) interactions — up sincos carried from previous row
        #pragma unroll
        for (int j = 0; j < 4; ++j)
            acc0 += cU[j] * cc[j] + sU[j] * s[j] * __cosf(pU[j] - pv[j]);

        // horizontal (left) interactions
        acc1 += cl * cc[0] + sl * s[0] * __cosf(PL - pv[0]);
        #pragma unroll
        for (int j = 1; j < 4; ++j)
            acc1 += cc[j-1] * cc[j] + s[j-1] * s[j] * __cosf(pv[j-1] - pv[j]);

        // current row becomes "up" for the next row
        #pragma unroll
        for (int j = 0; j < 4; ++j) { sU[j] = s[j]; cU[j] = cc[j]; pU[j] = pv[j]; }
    }

    // ---- block reduction: 64-lane butterfly, then 4 waves via LDS
    float acc = acc0 + acc1;
    #pragma unroll
    for (int off = 32; off >= 1; off >>= 1)
        acc += __shfl_down(acc, off, 64);

    __shared__ float red[THREADS / 64];
    if (lane == 0) red[wave] = acc;
    __syncthreads();
    if (threadIdx.x == 0)
        ws[blk] = red[0] + red[1] + red[2] + red[3];
}

__global__ __launch_bounds__(N_STATES)
void action_final(const float* __restrict__ ws, float* __restrict__ out)
{
    const int n = threadIdx.x;   // one thread per state
    float s = 0.0f;
    #pragma unroll
    for (int b = 0; b < BPS; ++b) s += ws[n * BPS + b];
    out[n] = ACTION_SHIFT_F - s;   // -BETA * sum + shift, BETA = 1
}

extern "C" void kernel_launch(void* const* d_in, const int* in_sizes, int n_in,
                              void* d_out, int out_size, void* d_ws, size_t ws_size,
                              hipStream_t stream)
{
    const float* state = (const float*)d_in[0];
    // d_in[1] (shift table) is the fixed torus-neighbor map; computed analytically.
    float* ws  = (float*)d_ws;
    float* out = (float*)d_out;

    action_partial<<<dim3(N_STATES * BPS), dim3(THREADS), 0, stream>>>(state, ws);
    action_final<<<dim3(1), dim3(N_STATES), 0, stream>>>(ws, out);
}

// Round 8
// 27.583 us; speedup vs baseline: 1.4298x; 1.4298x over previous
//
#include <hip/hip_runtime.h>

#define LENGTH   256
#define VOLUME   (LENGTH * LENGTH)
#define N_STATES 256
#define ACTION_SHIFT_F 131072.0f   // 2 * BETA * VOLUME, BETA = 1
#define BPS      8                 // blocks per state
#define EPB      (VOLUME / BPS)    // 8192 elements per block
#define THREADS  256
#define NGROUPS  (EPB / (4 * THREADS))   // 8 float4-groups per thread

// R1's proven frame (2048x256 grid, load-everything inner, two-kernel fold)
// with the loop kept at unroll 1 so the live set stays ~50 VGPR and
// __launch_bounds__(256, 8) yields 8 waves/SIMD WITHOUT spills.
// Latency hiding comes from TLP (8 waves) instead of unrolled ILP:
// per group each wave issues 6 independent loads, waits once, then has
// ~250 cyc of sincos/FMA work while the other 7 waves' loads fly.
__global__ __launch_bounds__(THREADS, 8)
void action_partial(const float* __restrict__ state, float* __restrict__ ws)
{
    const int blk = blockIdx.x;
    const int n   = blk >> 3;      // state index
    const int b   = blk & 7;       // chunk within state
    const float* __restrict__ theta = state + (size_t)n * (2 * VOLUME);
    const float* __restrict__ phi   = theta + VOLUME;
    const int base = b * EPB;

    float acc0 = 0.0f;   // vertical interactions
    float acc1 = 0.0f;   // horizontal interactions

    #pragma unroll 1
    for (int g = 0; g < NGROUPS; ++g) {
        const int i = base + ((g * THREADS) + (int)threadIdx.x) * 4;

        // ---- all 6 independent loads issued up front, one wait before use
        const float4 tc = *reinterpret_cast<const float4*>(theta + i);
        const float4 pc = *reinterpret_cast<const float4*>(phi   + i);

        const int up = (i >= LENGTH) ? (i - LENGTH) : (i + (VOLUME - LENGTH));
        const float4 tu = *reinterpret_cast<const float4*>(theta + up);
        const float4 pu = *reinterpret_cast<const float4*>(phi   + up);

        const int c0 = i & (LENGTH - 1);
        const int l0 = (c0 == 0) ? (i + (LENGTH - 1)) : (i - 1);
        const float tl = theta[l0];
        const float pl = phi[l0];

        const float tcv[4] = {tc.x, tc.y, tc.z, tc.w};
        const float pcv[4] = {pc.x, pc.y, pc.z, pc.w};
        const float tuv[4] = {tu.x, tu.y, tu.z, tu.w};
        const float puv[4] = {pu.x, pu.y, pu.z, pu.w};

        float sc[4], cc[4], su[4], cu[4];
        #pragma unroll
        for (int j = 0; j < 4; ++j) {
            __sincosf(tcv[j], &sc[j], &cc[j]);
            __sincosf(tuv[j], &su[j], &cu[j]);
        }
        float sl, cl;
        __sincosf(tl, &sl, &cl);

        // vertical (up) interactions
        #pragma unroll
        for (int j = 0; j < 4; ++j)
            acc0 += cu[j] * cc[j] + su[j] * sc[j] * __cosf(puv[j] - pcv[j]);

        // horizontal (left) interactions; reuse center sincos as neighbor
        acc1 += cl * cc[0] + sl * sc[0] * __cosf(pl - pcv[0]);
        #pragma unroll
        for (int j = 1; j < 4; ++j)
            acc1 += cc[j-1] * cc[j] + sc[j-1] * sc[j] * __cosf(pcv[j-1] - pcv[j]);
    }

    // ---- block reduction: 64-lane butterfly, then 4 waves via LDS
    float acc = acc0 + acc1;
    #pragma unroll
    for (int off = 32; off >= 1; off >>= 1)
        acc += __shfl_down(acc, off, 64);

    __shared__ float red[THREADS / 64];
    const int wave = threadIdx.x >> 6;
    const int lane = threadIdx.x & 63;
    if (lane == 0) red[wave] = acc;
    __syncthreads();
    if (threadIdx.x == 0)
        ws[blk] = red[0] + red[1] + red[2] + red[3];
}

__global__ __launch_bounds__(N_STATES)
void action_final(const float* __restrict__ ws, float* __restrict__ out)
{
    const int n = threadIdx.x;   // one thread per state
    float s = 0.0f;
    #pragma unroll
    for (int b = 0; b < BPS; ++b) s += ws[n * BPS + b];
    out[n] = ACTION_SHIFT_F - s;   // -BETA * sum + shift, BETA = 1
}

extern "C" void kernel_launch(void* const* d_in, const int* in_sizes, int n_in,
                              void* d_out, int out_size, void* d_ws, size_t ws_size,
                              hipStream_t stream)
{
    const float* state = (const float*)d_in[0];
    // d_in[1] (shift table) is the fixed torus-neighbor map; computed analytically.
    float* ws  = (float*)d_ws;
    float* out = (float*)d_out;

    action_partial<<<dim3(N_STATES * BPS), dim3(THREADS), 0, stream>>>(state, ws);
    action_final<<<dim3(1), dim3(N_STATES), 0, stream>>>(ws, out);
}